// Round 6
// baseline (175.133 us; speedup 1.0000x reference)
//
#include <hip/hip_runtime.h>

// YOLO-style loss: pred/target (16384, 7, 7, 14) fp32 -> scalar fp32.
// N = 14 channels: [0..4] box0 (x,y,w,h,conf), [5..9] box1, [10..13] classes.
//
// Round-4 structure: ONE WAVE per block, 64 pairs (128 cells), 14 KB LDS ->
// 11 blocks/CU, all at independent phases => HBM pipe never idles behind a
// barrier (there are NO barriers: LDS tile is wave-private, so a single
// inline-asm s_waitcnt vmcnt(0) orders gload_lds -> ds_read).
// Staging: 14x global_load_lds_dwordx4, each 64 consecutive float4 = 1 KB
// perfectly coalesced. Compute reads at float4-stride 7: gcd(7,8)=1 ->
// ds_read_b128 conflict-free without padding.

#define NPAIRS (16384 * 7 * 7 / 2)   // 401408
#define TPB 64
#define PPB 64                        // pairs per block (= per wave)
#define SLOTS (PPB * 7)               // 448 float4 slots per tensor (7 KB)

typedef __attribute__((address_space(3))) void lds_void;
typedef const __attribute__((address_space(1))) void glb_void;

__device__ __forceinline__ float cell_loss(const float* __restrict__ p,
                                           const float* __restrict__ t) {
    const float conf_t = t[4];
    const float coord = (conf_t > 0.0f) ? 1.0f : 0.0f;

    // target box 0
    const float tx = t[0] / 7.0f;
    const float ty = t[1] / 7.0f;
    const float tw = t[2];
    const float th = t[3];
    const float tlx = tx - 0.5f * tw, tly = ty - 0.5f * th;
    const float trx = tx + 0.5f * tw, trY = ty + 0.5f * th;
    const float area_t = (trx - tlx) * (trY - tly);

    float iou0, iou1;
    {
        const float px = p[0] / 7.0f, py = p[1] / 7.0f;
        const float pw = p[2], ph = p[3];
        const float plx = px - 0.5f * pw, ply = py - 0.5f * ph;
        const float prx = px + 0.5f * pw, prY = py + 0.5f * ph;
        const float ltx = fmaxf(plx, tlx), lty = fmaxf(ply, tly);
        const float rbx = fminf(prx, trx), rby = fminf(prY, trY);
        const float wx = fmaxf(rbx - ltx, 0.0f), wy = fmaxf(rby - lty, 0.0f);
        const float inter = wx * wy;
        const float area_p = (prx - plx) * (prY - ply);
        iou0 = inter / (area_p + area_t - inter);
    }
    {
        const float px = p[5] / 7.0f, py = p[6] / 7.0f;
        const float pw = p[7], ph = p[8];
        const float plx = px - 0.5f * pw, ply = py - 0.5f * ph;
        const float prx = px + 0.5f * pw, prY = py + 0.5f * ph;
        const float ltx = fmaxf(plx, tlx), lty = fmaxf(ply, tly);
        const float rbx = fminf(prx, trx), rby = fminf(prY, trY);
        const float wx = fmaxf(rbx - ltx, 0.0f), wy = fmaxf(rby - lty, 0.0f);
        const float inter = wx * wy;
        const float area_p = (prx - plx) * (prY - ply);
        iou1 = inter / (area_p + area_t - inter);
    }

    // jnp.argmax: first max wins -> box1 only if strictly greater.
    const bool sel1 = (iou1 > iou0);
    const float max_iou = fmaxf(iou0, iou1);

    // Branchless responsible-box select with STATIC indexing (no scratch).
    const float rp0 = sel1 ? p[5] : p[0];
    const float rp1 = sel1 ? p[6] : p[1];
    const float rp2 = sel1 ? p[7] : p[2];
    const float rp3 = sel1 ? p[8] : p[3];
    const float rp4 = sel1 ? p[9] : p[4];
    const float rt0 = sel1 ? t[5] : t[0];
    const float rt1 = sel1 ? t[6] : t[1];
    const float rt2 = sel1 ? t[7] : t[2];
    const float rt3 = sel1 ? t[8] : t[3];

    const float dx = rp0 - rt0;
    const float dy = rp1 - rt1;
    const float l_xy = dx * dx + dy * dy;

    const float sw = sqrtf(rp2) - sqrtf(rt2);
    const float sh = sqrtf(rp3) - sqrtf(rt3);
    const float l_wh = sw * sw + sh * sh;

    const float dobj = rp4 - max_iou;
    const float l_obj = dobj * dobj;

    float l_cls = 0.0f;
#pragma unroll
    for (int c = 10; c < 14; ++c) {
        const float pc = p[c];
        const float tc = t[c];
        l_cls += -(tc * logf(pc) + (1.0f - tc) * logf(1.0f - pc));
    }

    // df loss (unmasked)
    const float q = conf_t;
    const float pp = p[4];
    const float alpha = (1.0f - q) / (1.0f - pp);
    const float l_df = alpha * (pp - q) * logf(pp) + (q - pp) * logf(1.0f - pp);

    return coord * (l_xy + l_wh + l_obj + l_cls) + l_df;
}

__global__ __launch_bounds__(TPB) void yolo_loss_kernel(
    const float* __restrict__ pred, const float* __restrict__ tgt,
    float* __restrict__ out) {
    __shared__ float4 sp[SLOTS];   // 7 KB
    __shared__ float4 st[SLOTS];   // 7 KB  (14 KB total -> 11 blocks/CU)

    const int lane = threadIdx.x;  // one wave per block

    const long base4 = (long)blockIdx.x * SLOTS;  // tile base in float4 units
    const float4* __restrict__ gp = reinterpret_cast<const float4*>(pred) + base4;
    const float4* __restrict__ gt = reinterpret_cast<const float4*>(tgt) + base4;

    // 14 staging instructions, each 64 consecutive float4 (1 KB coalesced).
#pragma unroll
    for (int it = 0; it < 7; ++it) {
        const int s = it * 64;     // wave-uniform slot base
        __builtin_amdgcn_global_load_lds((glb_void*)(gp + s + lane),
                                         (lds_void*)(sp + s), 16, 0, 0);
        __builtin_amdgcn_global_load_lds((glb_void*)(gt + s + lane),
                                         (lds_void*)(st + s), 16, 0, 0);
    }
    // LDS tile is wave-private: no barrier needed, just drain the LDS-DMA.
    asm volatile("s_waitcnt vmcnt(0)" ::: "memory");

    // Per-thread pair: 7 float4 per tensor at slot-stride 7 (gcd(7,8)=1 ->
    // conflict-free ds_read_b128).
    float lp[28];
    float lt[28];
#pragma unroll
    for (int j = 0; j < 7; ++j) {
        const int s = 7 * lane + j;
        reinterpret_cast<float4*>(lp)[j] = sp[s];
        reinterpret_cast<float4*>(lt)[j] = st[s];
    }

    float v = cell_loss(lp, lt) + cell_loss(lp + 14, lt + 14);

    // wave-64 reduce, then one atomic per block.
#pragma unroll
    for (int off = 32; off > 0; off >>= 1) v += __shfl_down(v, off, 64);
    if (lane == 0) atomicAdd(out, v);
}

extern "C" void kernel_launch(void* const* d_in, const int* in_sizes, int n_in,
                              void* d_out, int out_size, void* d_ws, size_t ws_size,
                              hipStream_t stream) {
    const float* pred = (const float*)d_in[0];
    const float* tgt  = (const float*)d_in[1];
    float* out = (float*)d_out;

    // d_out is re-poisoned 0xAA before every timed launch -> zero it first.
    hipMemsetAsync(out, 0, sizeof(float), stream);

    const int blocks = NPAIRS / PPB;  // 6272, exact
    yolo_loss_kernel<<<blocks, TPB, 0, stream>>>(pred, tgt, out);
}

// Round 9
// 110.151 us; speedup vs baseline: 1.5899x; 1.5899x over previous
//
#include <hip/hip_runtime.h>

// YOLO-style loss: pred/target (16384, 7, 7, 14) fp32 -> scalar fp32.
// N = 14 channels: [0..4] box0 (x,y,w,h,conf), [5..9] box1, [10..13] classes.
//
// Round-7: round-6 streaming structure (1 wave/block, 64 pairs, 14 KB LDS,
// no barriers, global_load_lds staging + stride-7 ds_read_b128), but the
// per-block result is a PLAIN STORE to d_ws[blockIdx] instead of a
// same-address atomicAdd (round-6 counters: 90 us @ 6% HBM, VALUBusy 8.8%
// => 6272 serialized same-line atomics ~14 ns each were the entire cost).
// A second 1-block kernel reduces the 6272 partials and writes d_out.

#define NPAIRS (16384 * 7 * 7 / 2)   // 401408
#define TPB 64
#define PPB 64                        // pairs per block (= per wave)
#define SLOTS (PPB * 7)               // 448 float4 slots per tensor (7 KB)
#define NBLOCKS (NPAIRS / PPB)        // 6272, exact

typedef __attribute__((address_space(3))) void lds_void;
typedef const __attribute__((address_space(1))) void glb_void;

__device__ __forceinline__ float cell_loss(const float* __restrict__ p,
                                           const float* __restrict__ t) {
    const float conf_t = t[4];
    const float coord = (conf_t > 0.0f) ? 1.0f : 0.0f;

    // target box 0
    const float tx = t[0] / 7.0f;
    const float ty = t[1] / 7.0f;
    const float tw = t[2];
    const float th = t[3];
    const float tlx = tx - 0.5f * tw, tly = ty - 0.5f * th;
    const float trx = tx + 0.5f * tw, trY = ty + 0.5f * th;
    const float area_t = (trx - tlx) * (trY - tly);

    float iou0, iou1;
    {
        const float px = p[0] / 7.0f, py = p[1] / 7.0f;
        const float pw = p[2], ph = p[3];
        const float plx = px - 0.5f * pw, ply = py - 0.5f * ph;
        const float prx = px + 0.5f * pw, prY = py + 0.5f * ph;
        const float ltx = fmaxf(plx, tlx), lty = fmaxf(ply, tly);
        const float rbx = fminf(prx, trx), rby = fminf(prY, trY);
        const float wx = fmaxf(rbx - ltx, 0.0f), wy = fmaxf(rby - lty, 0.0f);
        const float inter = wx * wy;
        const float area_p = (prx - plx) * (prY - ply);
        iou0 = inter / (area_p + area_t - inter);
    }
    {
        const float px = p[5] / 7.0f, py = p[6] / 7.0f;
        const float pw = p[7], ph = p[8];
        const float plx = px - 0.5f * pw, ply = py - 0.5f * ph;
        const float prx = px + 0.5f * pw, prY = py + 0.5f * ph;
        const float ltx = fmaxf(plx, tlx), lty = fmaxf(ply, tly);
        const float rbx = fminf(prx, trx), rby = fminf(prY, trY);
        const float wx = fmaxf(rbx - ltx, 0.0f), wy = fmaxf(rby - lty, 0.0f);
        const float inter = wx * wy;
        const float area_p = (prx - plx) * (prY - ply);
        iou1 = inter / (area_p + area_t - inter);
    }

    // jnp.argmax: first max wins -> box1 only if strictly greater.
    const bool sel1 = (iou1 > iou0);
    const float max_iou = fmaxf(iou0, iou1);

    // Branchless responsible-box select with STATIC indexing (no scratch).
    const float rp0 = sel1 ? p[5] : p[0];
    const float rp1 = sel1 ? p[6] : p[1];
    const float rp2 = sel1 ? p[7] : p[2];
    const float rp3 = sel1 ? p[8] : p[3];
    const float rp4 = sel1 ? p[9] : p[4];
    const float rt0 = sel1 ? t[5] : t[0];
    const float rt1 = sel1 ? t[6] : t[1];
    const float rt2 = sel1 ? t[7] : t[2];
    const float rt3 = sel1 ? t[8] : t[3];

    const float dx = rp0 - rt0;
    const float dy = rp1 - rt1;
    const float l_xy = dx * dx + dy * dy;

    const float sw = sqrtf(rp2) - sqrtf(rt2);
    const float sh = sqrtf(rp3) - sqrtf(rt3);
    const float l_wh = sw * sw + sh * sh;

    const float dobj = rp4 - max_iou;
    const float l_obj = dobj * dobj;

    float l_cls = 0.0f;
#pragma unroll
    for (int c = 10; c < 14; ++c) {
        const float pc = p[c];
        const float tc = t[c];
        l_cls += -(tc * logf(pc) + (1.0f - tc) * logf(1.0f - pc));
    }

    // df loss (unmasked)
    const float q = conf_t;
    const float pp = p[4];
    const float alpha = (1.0f - q) / (1.0f - pp);
    const float l_df = alpha * (pp - q) * logf(pp) + (q - pp) * logf(1.0f - pp);

    return coord * (l_xy + l_wh + l_obj + l_cls) + l_df;
}

__global__ __launch_bounds__(TPB) void yolo_loss_kernel(
    const float* __restrict__ pred, const float* __restrict__ tgt,
    float* __restrict__ partials) {
    __shared__ float4 sp[SLOTS];   // 7 KB
    __shared__ float4 st[SLOTS];   // 7 KB  (14 KB total -> 11 blocks/CU)

    const int lane = threadIdx.x;  // one wave per block

    const long base4 = (long)blockIdx.x * SLOTS;  // tile base in float4 units
    const float4* __restrict__ gp = reinterpret_cast<const float4*>(pred) + base4;
    const float4* __restrict__ gt = reinterpret_cast<const float4*>(tgt) + base4;

    // 14 staging instructions, each 64 consecutive float4 (1 KB coalesced).
#pragma unroll
    for (int it = 0; it < 7; ++it) {
        const int s = it * 64;     // wave-uniform slot base
        __builtin_amdgcn_global_load_lds((glb_void*)(gp + s + lane),
                                         (lds_void*)(sp + s), 16, 0, 0);
        __builtin_amdgcn_global_load_lds((glb_void*)(gt + s + lane),
                                         (lds_void*)(st + s), 16, 0, 0);
    }
    // LDS tile is wave-private: no barrier needed, just drain the LDS-DMA.
    asm volatile("s_waitcnt vmcnt(0)" ::: "memory");

    // Per-thread pair: 7 float4 per tensor at slot-stride 7 (gcd(7,8)=1).
    float lp[28];
    float lt[28];
#pragma unroll
    for (int j = 0; j < 7; ++j) {
        const int s = 7 * lane + j;
        reinterpret_cast<float4*>(lp)[j] = sp[s];
        reinterpret_cast<float4*>(lt)[j] = st[s];
    }

    float v = cell_loss(lp, lt) + cell_loss(lp + 14, lt + 14);

    // wave-64 reduce, then ONE PLAIN STORE per block (no atomic).
#pragma unroll
    for (int off = 32; off > 0; off >>= 1) v += __shfl_down(v, off, 64);
    if (lane == 0) partials[blockIdx.x] = v;
}

__global__ __launch_bounds__(256) void reduce_kernel(
    const float* __restrict__ partials, float* __restrict__ out) {
    const int tid = threadIdx.x;
    float v = 0.0f;
    for (int i = tid; i < NBLOCKS; i += 256) v += partials[i];
#pragma unroll
    for (int off = 32; off > 0; off >>= 1) v += __shfl_down(v, off, 64);
    __shared__ float s[4];
    const int lane = tid & 63;
    const int wid = tid >> 6;
    if (lane == 0) s[wid] = v;
    __syncthreads();
    if (tid == 0) out[0] = s[0] + s[1] + s[2] + s[3];
}

extern "C" void kernel_launch(void* const* d_in, const int* in_sizes, int n_in,
                              void* d_out, int out_size, void* d_ws, size_t ws_size,
                              hipStream_t stream) {
    const float* pred = (const float*)d_in[0];
    const float* tgt  = (const float*)d_in[1];
    float* out = (float*)d_out;
    float* partials = (float*)d_ws;   // needs 6272 * 4 B = 25 KB of scratch

    yolo_loss_kernel<<<NBLOCKS, TPB, 0, stream>>>(pred, tgt, partials);
    reduce_kernel<<<1, 256, 0, stream>>>(partials, out);
}